// Round 6
// baseline (6660.366 us; speedup 1.0000x reference)
//
#include <hip/hip_runtime.h>

// ---- problem constants (b=16, f=8, p=196, dim=768, H=12) ----
#define NB   16
#define NH   12
#define NSEQ 1569
#define DIMM 768
#define PDIM 196
#define FF   8
#define DH   64
#define MROWS (NB * NSEQ)   // 25104

typedef short short8 __attribute__((ext_vector_type(8)));

__device__ __forceinline__ float bf2f(ushort u) {
    union { uint i; float f; } w; w.i = ((uint)u) << 16; return w.f;
}
__device__ __forceinline__ float bflo(uint p) {
    union { uint i; float f; } w; w.i = p << 16; return w.f;
}
__device__ __forceinline__ float bfhi(uint p) {
    union { uint i; float f; } w; w.i = p & 0xFFFF0000u; return w.f;
}
__device__ __forceinline__ ushort f2bf(float f) {
    union { float f; uint i; } w; w.f = f;
    uint x = w.i;
    return (ushort)((x + 0x7FFFu + ((x >> 16) & 1u)) >> 16);
}
// inputs are fp32 per the reference; keep a dtype flag for robustness
__device__ __forceinline__ float in_ld(const void* p, size_t idx, int f32) {
    return f32 ? ((const float*)p)[idx] : bf2f(((const ushort*)p)[idx]);
}

__global__ void detect_dtype(const ushort* __restrict__ w, int* __restrict__ flags)
{
    __shared__ int anyBig;
    if (threadIdx.x == 0) anyBig = 0;
    __syncthreads();
    for (int i = threadIdx.x; i < 2048; i += 256) {
        int e = (w[i] >> 7) & 0xFF;
        if (e >= 134) anyBig = 1;   // fp32-as-ushort has random exponents
    }
    __syncthreads();
    if (threadIdx.x == 0) flags[0] = anyBig;
}

// ======================= naive QKV GEMM (fp32 vector) =======================
// qkv[M][2304] = x[M][768] @ Wqkv[768][2304]; scatter q(*0.125)/k/v into
// head-major bf16 workspace [b*h][n][64].
#define NBM 64
#define NBN 64
#define NBK 16

__global__ __launch_bounds__(256)
void qkv_naive(const void* __restrict__ A, const void* __restrict__ B,
               ushort* __restrict__ o0, ushort* __restrict__ o1,
               ushort* __restrict__ o2, int M, int N, int K,
               const int* __restrict__ flags)
{
    __shared__ float As[NBM][NBK + 1];
    __shared__ float Bs[NBK][NBN + 1];

    const int fl  = flags[0];
    const int nbn = N / NBN;
    const int mb  = blockIdx.x / nbn;
    const int nb  = blockIdx.x % nbn;
    const int Mb  = mb * NBM, Nbs = nb * NBN;

    const int tid = threadIdx.x;
    const int tr  = tid >> 4;
    const int tc  = tid & 15;

    float acc[4][4];
#pragma unroll
    for (int i = 0; i < 4; ++i)
#pragma unroll
        for (int j = 0; j < 4; ++j) acc[i][j] = 0.f;

    for (int k0 = 0; k0 < K; k0 += NBK) {
#pragma unroll
        for (int c = 0; c < 4; ++c) {
            int e = tid + c * 256;
            int r = e >> 4, kk = e & 15;
            int gr = Mb + r; if (gr >= M) gr = M - 1;
            float va = in_ld(A, (size_t)gr * K + k0 + kk, fl);
            As[r][kk] = bf2f(f2bf(va));   // bf16-round to match MFMA path later
        }
#pragma unroll
        for (int c = 0; c < 4; ++c) {
            int e = tid + c * 256;
            int kr = e >> 6, n = e & 63;
            float vb = in_ld(B, (size_t)(k0 + kr) * N + Nbs + n, fl);
            Bs[kr][n] = bf2f(f2bf(vb));
        }
        __syncthreads();
#pragma unroll
        for (int kk = 0; kk < NBK; ++kk) {
            float a[4], b[4];
#pragma unroll
            for (int i = 0; i < 4; ++i) a[i] = As[tr * 4 + i][kk];
#pragma unroll
            for (int j = 0; j < 4; ++j) b[j] = Bs[kk][tc * 4 + j];
#pragma unroll
            for (int i = 0; i < 4; ++i)
#pragma unroll
                for (int j = 0; j < 4; ++j)
                    acc[i][j] = fmaf(a[i], b[j], acc[i][j]);
        }
        __syncthreads();
    }

#pragma unroll
    for (int i = 0; i < 4; ++i) {
        int row = Mb + tr * 4 + i;
        if (row >= M) continue;
        int b = row / NSEQ, nn = row - b * NSEQ;
#pragma unroll
        for (int j = 0; j < 4; ++j) {
            int col = Nbs + tc * 4 + j;
            int which = (col >= 2 * DIMM) ? 2 : (col >= DIMM ? 1 : 0);
            int rem = col - which * DIMM;
            int hi = rem >> 6, di = rem & 63;
            ushort* dst = (which == 0) ? o0 : (which == 1 ? o1 : o2);
            float sc = (which == 0) ? 0.125f : 1.0f;
            dst[(((size_t)b * NH + hi) * NSEQ + nn) * DH + di] = f2bf(acc[i][j] * sc);
        }
    }
}

// ======================= CLS attention (fp32 out) =======================
__global__ __launch_bounds__(256)
void cls_attn(const ushort* __restrict__ q, const ushort* __restrict__ k,
              const ushort* __restrict__ v, const void* __restrict__ mask,
              float* __restrict__ out, const int* __restrict__ flags)
{
    const int fl = flags[0];
    const int bh = blockIdx.x;
    const int bi = bh / NH, hi = bh - bi * NH;
    const int tid = threadIdx.x, lane = tid & 63, wid = tid >> 6;

    __shared__ float qs[DH];
    __shared__ float simbuf[NSEQ];
    __shared__ float redm[4], redl[4];
    __shared__ float osum[4][DH];

    if (tid < DH) qs[tid] = bf2f(q[((size_t)bh * NSEQ) * DH + tid]);
    __syncthreads();

    for (int j = tid; j < NSEQ; j += 256) {
        const ushort* kr = k + ((size_t)bh * NSEQ + j) * DH;
        float s = 0.f;
#pragma unroll
        for (int c = 0; c < 8; ++c) {
            union { uint4 u; ushort e[8]; } w;
            w.u = *(const uint4*)(kr + c * 8);
#pragma unroll
            for (int i = 0; i < 8; ++i) s += qs[c * 8 + i] * bf2f(w.e[i]);
        }
        int sp = (j == 0) ? 0 : 1 + ((j - 1) % PDIM);
        s += (1.0f - in_ld(mask, bi * (1 + PDIM) + sp, fl)) * -10000.0f;
        simbuf[j] = s;
    }
    __syncthreads();

    float m = -3e38f;
    for (int j = tid; j < NSEQ; j += 256) m = fmaxf(m, simbuf[j]);
#pragma unroll
    for (int o = 32; o > 0; o >>= 1) m = fmaxf(m, __shfl_xor(m, o));
    if (lane == 0) redm[wid] = m;
    __syncthreads();
    m = fmaxf(fmaxf(redm[0], redm[1]), fmaxf(redm[2], redm[3]));

    float ls = 0.f;
    for (int j = tid; j < NSEQ; j += 256) {
        float p = __expf(simbuf[j] - m);
        simbuf[j] = p;
        ls += p;
    }
#pragma unroll
    for (int o = 32; o > 0; o >>= 1) ls += __shfl_xor(ls, o);
    if (lane == 0) redl[wid] = ls;
    __syncthreads();
    float l = redl[0] + redl[1] + redl[2] + redl[3];

    int g = wid, di = tid & 63;
    float acc = 0.f;
    for (int j = g; j < NSEQ; j += 4)
        acc += simbuf[j] * bf2f(v[((size_t)bh * NSEQ + j) * DH + di]);
    osum[g][di] = acc;
    __syncthreads();
    if (tid < DH) {
        float o = (osum[0][tid] + osum[1][tid] + osum[2][tid] + osum[3][tid]) / l;
        out[((size_t)bi * NSEQ) * DIMM + hi * DH + tid] = o;   // fp32 store
    }
}

// ======================= spatial attention (fp32 out) =======================
__global__ __launch_bounds__(256)
void spatial_attn(const ushort* __restrict__ q, const ushort* __restrict__ k,
                  const ushort* __restrict__ v, const void* __restrict__ mask,
                  float* __restrict__ out, const int* __restrict__ flags)
{
    const int fl = flags[0];
    const int bhf = blockIdx.x;
    const int bh = bhf >> 3, fi = bhf & 7;
    const int bi = bh / NH, hi = bh - bi * NH;
    const int tid = threadIdx.x;

    __shared__ __align__(16) ushort k2s[197 * DH];
    __shared__ __align__(16) ushort v2s[197 * DH];
    __shared__ float bias_s[197];

    if (tid < 197)
        bias_s[tid] = (1.0f - in_ld(mask, bi * 197 + tid, fl)) * -10000.0f;

    for (int c = tid; c < 197 * DH / 8; c += 256) {
        int j = c >> 3, off = (c & 7) * 8;
        int row = (j == 0) ? 0 : (fi * PDIM + j);
        size_t src = ((size_t)bh * NSEQ + row) * DH + off;
        *(uint4*)&k2s[j * DH + off] = *(const uint4*)(k + src);
        *(uint4*)&v2s[j * DH + off] = *(const uint4*)(v + src);
    }
    __syncthreads();

    const int qi = tid;
    if (qi >= PDIM) return;

    const int ni = 1 + fi * PDIM + qi;
    const ushort* qr = q + ((size_t)bh * NSEQ + ni) * DH;
    float q_r[DH];
#pragma unroll
    for (int c = 0; c < 8; ++c) {
        union { uint4 u; ushort e[8]; } w;
        w.u = *(const uint4*)(qr + c * 8);
#pragma unroll
        for (int i = 0; i < 8; ++i) q_r[c * 8 + i] = bf2f(w.e[i]);
    }

    float o[DH];
#pragma unroll
    for (int i = 0; i < DH; ++i) o[i] = 0.f;
    float m = -3e38f, l = 0.f;

    for (int j = 0; j < 197; ++j) {
        const ushort* kr = &k2s[j * DH];
        float s = bias_s[j];
#pragma unroll
        for (int i = 0; i < DH; i += 2) {
            uint pk = *(const uint*)(kr + i);
            s += q_r[i] * bflo(pk) + q_r[i + 1] * bfhi(pk);
        }
        float mn = fmaxf(m, s);
        float alpha = __expf(m - mn);
        float p = __expf(s - mn);
        l = l * alpha + p;
        const ushort* vr = &v2s[j * DH];
#pragma unroll
        for (int i = 0; i < DH; i += 2) {
            uint pv = *(const uint*)(vr + i);
            o[i]     = o[i] * alpha + p * bflo(pv);
            o[i + 1] = o[i + 1] * alpha + p * bfhi(pv);
        }
        m = mn;
    }

    float inv = 1.0f / l;
    float* base = out + ((size_t)bi * NSEQ + ni) * DIMM + hi * DH;
#pragma unroll
    for (int c = 0; c < 16; ++c) {   // 16 x float4 stores, 16B aligned
        float4 w;
        w.x = o[c * 4 + 0] * inv;
        w.y = o[c * 4 + 1] * inv;
        w.z = o[c * 4 + 2] * inv;
        w.w = o[c * 4 + 3] * inv;
        *(float4*)(base + c * 4) = w;
    }
}

// ======================= in-place stripe projection (fp32 io) =======================
// io[M][768] <- io @ W + bias.  One block per 64-row stripe; stripe staged
// (bf16-rounded) in LDS, so in-place is race-free per block.
__global__ __launch_bounds__(256)
void stripe_proj(float* __restrict__ io, const void* __restrict__ W,
                 const void* __restrict__ bias, const int* __restrict__ flags)
{
    __shared__ __align__(16) ushort Als[64][DIMM + 8];

    const int fl = flags[0];
    const int rbase = blockIdx.x * 64;
    const int tid = threadIdx.x;

    for (int c = tid; c < 64 * (DIMM / 8); c += 256) {
        int r = c / (DIMM / 8), off = (c % (DIMM / 8)) * 8;
        int row = rbase + r;
        union { uint4 u; ushort s[8]; } w;
        if (row < MROWS) {
            float4 f0 = *(const float4*)(io + (size_t)row * DIMM + off);
            float4 f1 = *(const float4*)(io + (size_t)row * DIMM + off + 4);
            w.s[0] = f2bf(f0.x); w.s[1] = f2bf(f0.y);
            w.s[2] = f2bf(f0.z); w.s[3] = f2bf(f0.w);
            w.s[4] = f2bf(f1.x); w.s[5] = f2bf(f1.y);
            w.s[6] = f2bf(f1.z); w.s[7] = f2bf(f1.w);
        } else {
            w.u = (uint4){0u, 0u, 0u, 0u};
        }
        *(uint4*)&Als[r][off] = w.u;
    }
    __syncthreads();

    for (int chunk = 0; chunk < 3; ++chunk) {
        int col = chunk * 256 + tid;
        float bv = in_ld(bias, col, fl);
        float acc[64];
#pragma unroll
        for (int r = 0; r < 64; ++r) acc[r] = bv;
        for (int k = 0; k < DIMM; k += 2) {
            float w0 = in_ld(W, (size_t)k * DIMM + col, fl);
            float w1 = in_ld(W, (size_t)(k + 1) * DIMM + col, fl);
#pragma unroll
            for (int r = 0; r < 64; ++r) {
                uint av = *(const uint*)&Als[r][k];
                acc[r] = fmaf(bflo(av), w0, fmaf(bfhi(av), w1, acc[r]));
            }
        }
#pragma unroll
        for (int r = 0; r < 64; ++r) {
            int row = rbase + r;
            if (row < MROWS)
                io[(size_t)row * DIMM + col] = acc[r];   // fp32 store
        }
    }
}

// ======================= launch =======================
extern "C" void kernel_launch(void* const* d_in, const int* in_sizes, int n_in,
                              void* d_out, int out_size, void* d_ws, size_t ws_size,
                              hipStream_t stream)
{
    const void* x     = d_in[0];
    const void* mask  = d_in[1];
    const void* Wqkv  = d_in[2];
    const void* Wproj = d_in[3];
    const void* bproj = d_in[4];
    float* out = (float*)d_out;          // reference output dtype = float32

    int*    flags = (int*)d_ws;
    ushort* base  = (ushort*)((char*)d_ws + 256);
    const size_t S = (size_t)NB * NH * NSEQ * DH;   // 19,279,872
    ushort* qb = base;
    ushort* kb = qb + S;
    ushort* vb = kb + S;

    const int M  = MROWS;
    const int gM = (M + 63) / 64;   // 393

    detect_dtype<<<1, 256, 0, stream>>>((const ushort*)Wqkv, flags);

    qkv_naive<<<gM * (3 * DIMM / NBN), 256, 0, stream>>>(
        x, Wqkv, qb, kb, vb, M, 3 * DIMM, DIMM, flags);

    cls_attn<<<NB * NH, 256, 0, stream>>>(qb, kb, vb, mask, out, flags);
    spatial_attn<<<NB * NH * FF, 256, 0, stream>>>(qb, kb, vb, mask, out, flags);
    stripe_proj<<<gM, 256, 0, stream>>>(out, Wproj, bproj, flags);
}

// Round 7
// 1413.037 us; speedup vs baseline: 4.7135x; 4.7135x over previous
//
#include <hip/hip_runtime.h>

// ---- problem constants (b=16, f=8, p=196, dim=768, H=12) ----
#define NB   16
#define NH   12
#define NSEQ 1569
#define DIMM 768
#define PDIM 196
#define FF   8
#define DH   64
#define MROWS (NB * NSEQ)   // 25104

typedef short short8 __attribute__((ext_vector_type(8)));
typedef float float4v __attribute__((ext_vector_type(4)));

__device__ __forceinline__ float bf2f(ushort u) {
    union { uint i; float f; } w; w.i = ((uint)u) << 16; return w.f;
}
__device__ __forceinline__ float bflo(uint p) {
    union { uint i; float f; } w; w.i = p << 16; return w.f;
}
__device__ __forceinline__ float bfhi(uint p) {
    union { uint i; float f; } w; w.i = p & 0xFFFF0000u; return w.f;
}
__device__ __forceinline__ ushort f2bf(float f) {
    union { float f; uint i; } w; w.f = f;
    uint x = w.i;
    return (ushort)((x + 0x7FFFu + ((x >> 16) & 1u)) >> 16);
}
__device__ __forceinline__ float in_ld(const void* p, size_t idx, int f32) {
    return f32 ? ((const float*)p)[idx] : bf2f(((const ushort*)p)[idx]);
}

__global__ void detect_dtype(const ushort* __restrict__ w, int* __restrict__ flags)
{
    __shared__ int anyBig;
    if (threadIdx.x == 0) anyBig = 0;
    __syncthreads();
    for (int i = threadIdx.x; i < 2048; i += 256) {
        int e = (w[i] >> 7) & 0xFF;
        if (e >= 134) anyBig = 1;   // fp32-as-ushort has random exponents
    }
    __syncthreads();
    if (threadIdx.x == 0) flags[0] = anyBig;
}

// ======================= 128x128 MFMA GEMM =======================
// C[M,N] = A[M,K] @ B[K,N], bf16 MFMA, fp32 acc.
// MODE 0: A,B raw inputs (dtype per flag); scatter q(*0.125)/k/v head-major bf16.
// MODE 1: A = bf16 workspace, B raw; out = fp32 d_out + bias.
#define BM 128
#define BN 128
#define BK 64
#define KP 8   // pad: row stride 72 ushorts = 144 B (16B-aligned, 2-way bank alias = free)

template<int MODE>
__global__ __launch_bounds__(256)
void gemm128(const void* __restrict__ A, const void* __restrict__ B,
             const void* __restrict__ bias,
             ushort* __restrict__ o0, ushort* __restrict__ o1,
             ushort* __restrict__ o2, float* __restrict__ of,
             int M, int N, int K, const int* __restrict__ flags)
{
    __shared__ __align__(16) ushort As[BM][BK + KP];
    __shared__ __align__(16) ushort Bs[BN][BK + KP];   // transposed: [n][k]

    const int fl  = flags[0];
    const int nbn = N / BN;
    const int mb  = blockIdx.x / nbn;
    const int nb  = blockIdx.x % nbn;
    const int Mb  = mb * BM, Nbs = nb * BN;

    const int tid  = threadIdx.x;
    const int lane = tid & 63;
    const int wid  = tid >> 6;
    const int wr   = (wid >> 1) * 64;   // wave row offset
    const int wc   = (wid & 1) * 64;    // wave col offset
    const int q4   = lane >> 4;
    const int l16  = lane & 15;

    const float*  Af = (const float*)A;
    const ushort* Ab = (const ushort*)A;
    const float*  Bf = (const float*)B;
    const ushort* Bb = (const ushort*)B;

    float4v acc[4][4];
#pragma unroll
    for (int i = 0; i < 4; ++i)
#pragma unroll
        for (int j = 0; j < 4; ++j) acc[i][j] = (float4v){0.f, 0.f, 0.f, 0.f};

    for (int k0 = 0; k0 < K; k0 += BK) {
        // ---- stage A: 128x64 ----
        if (MODE == 1 || !fl) {     // bf16 source: 8192 elems, uint4 x4/thread
#pragma unroll
            for (int c = 0; c < 4; ++c) {
                int e = (tid + c * 256) * 8;
                int row = e >> 6, koff = e & 63;
                int gr = Mb + row; if (gr >= M) gr = M - 1;
                *(uint4*)&As[row][koff] = *(const uint4*)(Ab + (size_t)gr * K + k0 + koff);
            }
        } else {                    // fp32 source: float4 x8/thread, convert
#pragma unroll
            for (int c = 0; c < 8; ++c) {
                int e = (tid + c * 256) * 4;
                int row = e >> 6, koff = e & 63;
                int gr = Mb + row; if (gr >= M) gr = M - 1;
                float4 f = *(const float4*)(Af + (size_t)gr * K + k0 + koff);
                union { uint2 u; ushort s[4]; } w;
                w.s[0] = f2bf(f.x); w.s[1] = f2bf(f.y);
                w.s[2] = f2bf(f.z); w.s[3] = f2bf(f.w);
                *(uint2*)&As[row][koff] = w.u;
            }
        }
        // ---- stage B transposed: 64x128 -> Bs[n][k] ----
        if (fl) {
#pragma unroll
            for (int c = 0; c < 8; ++c) {
                int e = (tid + c * 256) * 4;
                int kr = e >> 7, noff = e & 127;
                float4 f = *(const float4*)(Bf + (size_t)(k0 + kr) * N + Nbs + noff);
                Bs[noff + 0][kr] = f2bf(f.x);
                Bs[noff + 1][kr] = f2bf(f.y);
                Bs[noff + 2][kr] = f2bf(f.z);
                Bs[noff + 3][kr] = f2bf(f.w);
            }
        } else {
#pragma unroll
            for (int c = 0; c < 4; ++c) {
                int e = (tid + c * 256) * 8;
                int kr = e >> 7, noff = e & 127;
                union { uint4 u; ushort s[8]; } w;
                w.u = *(const uint4*)(Bb + (size_t)(k0 + kr) * N + Nbs + noff);
#pragma unroll
                for (int i = 0; i < 8; ++i) Bs[noff + i][kr] = w.s[i];
            }
        }
        __syncthreads();

#pragma unroll
        for (int kk = 0; kk < BK; kk += 32) {
            short8 a[4], b[4];
#pragma unroll
            for (int t = 0; t < 4; ++t) {
                a[t] = *(const short8*)&As[wr + t * 16 + l16][kk + q4 * 8];
                b[t] = *(const short8*)&Bs[wc + t * 16 + l16][kk + q4 * 8];
            }
#pragma unroll
            for (int tr = 0; tr < 4; ++tr)
#pragma unroll
                for (int tc = 0; tc < 4; ++tc)
                    acc[tr][tc] = __builtin_amdgcn_mfma_f32_16x16x32_bf16(
                        a[tr], b[tc], acc[tr][tc], 0, 0, 0);
        }
        __syncthreads();
    }

    // ---- epilogue (C/D: row = q4*4+i, col = l16; HW-probe-verified H1) ----
#pragma unroll
    for (int tr = 0; tr < 4; ++tr)
#pragma unroll
        for (int tc = 0; tc < 4; ++tc) {
            int col = Nbs + wc + tc * 16 + l16;
            int rb  = Mb + wr + tr * 16 + q4 * 4;
            if (MODE == 0) {
                int which = (col >= 2 * DIMM) ? 2 : (col >= DIMM ? 1 : 0);
                int rem = col - which * DIMM;
                int hi = rem >> 6, di = rem & 63;
                ushort* dst = (which == 0) ? o0 : (which == 1 ? o1 : o2);
                float sc = (which == 0) ? 0.125f : 1.0f;
#pragma unroll
                for (int i = 0; i < 4; ++i) {
                    int row = rb + i;
                    if (row < M) {
                        int b = row / NSEQ, nn = row - b * NSEQ;
                        dst[(((size_t)b * NH + hi) * NSEQ + nn) * DH + di] =
                            f2bf(acc[tr][tc][i] * sc);
                    }
                }
            } else {
                float bv = in_ld(bias, col, fl);
#pragma unroll
                for (int i = 0; i < 4; ++i) {
                    int row = rb + i;
                    if (row < M)
                        of[(size_t)row * N + col] = acc[tr][tc][i] + bv;
                }
            }
        }
}

// ======================= CLS attention (bf16 ab out) =======================
__global__ __launch_bounds__(256)
void cls_attn(const ushort* __restrict__ q, const ushort* __restrict__ k,
              const ushort* __restrict__ v, const void* __restrict__ mask,
              ushort* __restrict__ ab, const int* __restrict__ flags)
{
    const int fl = flags[0];
    const int bh = blockIdx.x;
    const int bi = bh / NH, hi = bh - bi * NH;
    const int tid = threadIdx.x, lane = tid & 63, wid = tid >> 6;

    __shared__ float qs[DH];
    __shared__ float simbuf[NSEQ];
    __shared__ float redm[4], redl[4];
    __shared__ float osum[4][DH];

    if (tid < DH) qs[tid] = bf2f(q[((size_t)bh * NSEQ) * DH + tid]);
    __syncthreads();

    for (int j = tid; j < NSEQ; j += 256) {
        const ushort* kr = k + ((size_t)bh * NSEQ + j) * DH;
        float s = 0.f;
#pragma unroll
        for (int c = 0; c < 8; ++c) {
            union { uint4 u; ushort e[8]; } w;
            w.u = *(const uint4*)(kr + c * 8);
#pragma unroll
            for (int i = 0; i < 8; ++i) s += qs[c * 8 + i] * bf2f(w.e[i]);
        }
        int sp = (j == 0) ? 0 : 1 + ((j - 1) % PDIM);
        s += (1.0f - in_ld(mask, bi * (1 + PDIM) + sp, fl)) * -10000.0f;
        simbuf[j] = s;
    }
    __syncthreads();

    float m = -3e38f;
    for (int j = tid; j < NSEQ; j += 256) m = fmaxf(m, simbuf[j]);
#pragma unroll
    for (int o = 32; o > 0; o >>= 1) m = fmaxf(m, __shfl_xor(m, o));
    if (lane == 0) redm[wid] = m;
    __syncthreads();
    m = fmaxf(fmaxf(redm[0], redm[1]), fmaxf(redm[2], redm[3]));

    float ls = 0.f;
    for (int j = tid; j < NSEQ; j += 256) {
        float p = __expf(simbuf[j] - m);
        simbuf[j] = p;
        ls += p;
    }
#pragma unroll
    for (int o = 32; o > 0; o >>= 1) ls += __shfl_xor(ls, o);
    if (lane == 0) redl[wid] = ls;
    __syncthreads();
    float l = redl[0] + redl[1] + redl[2] + redl[3];

    int g = wid, di = tid & 63;
    float acc = 0.f;
    for (int j = g; j < NSEQ; j += 4)
        acc += simbuf[j] * bf2f(v[((size_t)bh * NSEQ + j) * DH + di]);
    osum[g][di] = acc;
    __syncthreads();
    if (tid < DH) {
        float o = (osum[0][tid] + osum[1][tid] + osum[2][tid] + osum[3][tid]) / l;
        ab[((size_t)bi * NSEQ) * DIMM + hi * DH + tid] = f2bf(o);
    }
}

// ======================= spatial attention (bf16 ab out) =======================
__global__ __launch_bounds__(256)
void spatial_attn(const ushort* __restrict__ q, const ushort* __restrict__ k,
                  const ushort* __restrict__ v, const void* __restrict__ mask,
                  ushort* __restrict__ ab, const int* __restrict__ flags)
{
    const int fl = flags[0];
    const int bhf = blockIdx.x;
    const int bh = bhf >> 3, fi = bhf & 7;
    const int bi = bh / NH, hi = bh - bi * NH;
    const int tid = threadIdx.x;

    __shared__ __align__(16) ushort k2s[197 * DH];
    __shared__ __align__(16) ushort v2s[197 * DH];
    __shared__ float bias_s[197];

    if (tid < 197)
        bias_s[tid] = (1.0f - in_ld(mask, bi * 197 + tid, fl)) * -10000.0f;

    for (int c = tid; c < 197 * DH / 8; c += 256) {
        int j = c >> 3, off = (c & 7) * 8;
        int row = (j == 0) ? 0 : (fi * PDIM + j);
        size_t src = ((size_t)bh * NSEQ + row) * DH + off;
        *(uint4*)&k2s[j * DH + off] = *(const uint4*)(k + src);
        *(uint4*)&v2s[j * DH + off] = *(const uint4*)(v + src);
    }
    __syncthreads();

    const int qi = tid;
    if (qi >= PDIM) return;

    const int ni = 1 + fi * PDIM + qi;
    const ushort* qr = q + ((size_t)bh * NSEQ + ni) * DH;
    float q_r[DH];
#pragma unroll
    for (int c = 0; c < 8; ++c) {
        union { uint4 u; ushort e[8]; } w;
        w.u = *(const uint4*)(qr + c * 8);
#pragma unroll
        for (int i = 0; i < 8; ++i) q_r[c * 8 + i] = bf2f(w.e[i]);
    }

    float o[DH];
#pragma unroll
    for (int i = 0; i < DH; ++i) o[i] = 0.f;
    float m = -3e38f, l = 0.f;

    for (int j = 0; j < 197; ++j) {
        const ushort* kr = &k2s[j * DH];
        float s = bias_s[j];
#pragma unroll
        for (int i = 0; i < DH; i += 2) {
            uint pk = *(const uint*)(kr + i);
            s += q_r[i] * bflo(pk) + q_r[i + 1] * bfhi(pk);
        }
        float mn = fmaxf(m, s);
        float alpha = __expf(m - mn);
        float p = __expf(s - mn);
        l = l * alpha + p;
        const ushort* vr = &v2s[j * DH];
#pragma unroll
        for (int i = 0; i < DH; i += 2) {
            uint pv = *(const uint*)(vr + i);
            o[i]     = o[i] * alpha + p * bflo(pv);
            o[i + 1] = o[i + 1] * alpha + p * bfhi(pv);
        }
        m = mn;
    }

    float inv = 1.0f / l;
    size_t base = ((size_t)bi * NSEQ + ni) * DIMM + hi * DH;
#pragma unroll
    for (int c = 0; c < 8; ++c) {
        union { uint4 u; ushort e[8]; } w;
#pragma unroll
        for (int i = 0; i < 8; ++i) w.e[i] = f2bf(o[c * 8 + i] * inv);
        *(uint4*)(ab + base + c * 8) = w.u;
    }
}

// ======================= launch =======================
extern "C" void kernel_launch(void* const* d_in, const int* in_sizes, int n_in,
                              void* d_out, int out_size, void* d_ws, size_t ws_size,
                              hipStream_t stream)
{
    const void* x     = d_in[0];
    const void* mask  = d_in[1];
    const void* Wqkv  = d_in[2];
    const void* Wproj = d_in[3];
    const void* bproj = d_in[4];
    float* out = (float*)d_out;          // reference output dtype = float32

    int*    flags = (int*)d_ws;
    ushort* base  = (ushort*)((char*)d_ws + 256);
    const size_t S = (size_t)NB * NH * NSEQ * DH;   // 19,279,872 (= MROWS*768)
    ushort* qb = base;
    ushort* kb = qb + S;
    ushort* vb = kb + S;
    ushort* ab = vb + S;                 // attention out, bf16 [M][768]

    const int M   = MROWS;
    const int gM  = (M + BM - 1) / BM;   // 197

    detect_dtype<<<1, 256, 0, stream>>>((const ushort*)Wqkv, flags);

    // 1) qkv = x @ Wqkv (MFMA), scatter head-major
    gemm128<0><<<gM * (3 * DIMM / BN), 256, 0, stream>>>(
        x, Wqkv, nullptr, qb, kb, vb, nullptr, M, 3 * DIMM, DIMM, flags);

    // 2) attention
    cls_attn<<<NB * NH, 256, 0, stream>>>(qb, kb, vb, mask, ab, flags);
    spatial_attn<<<NB * NH * FF, 256, 0, stream>>>(qb, kb, vb, mask, ab, flags);

    // 3) out = ab @ Wproj + bias (MFMA, fp32 out)
    gemm128<1><<<gM * (DIMM / BN), 256, 0, stream>>>(
        ab, Wproj, bproj, nullptr, nullptr, nullptr, out, M, DIMM, DIMM, flags);
}